// Round 15
// baseline (1491.363 us; speedup 1.0000x reference)
//
#include <hip/hip_runtime.h>

// RCNN forward. ALL convs on MFMA f16 (implicit GEMM); activations
// [n][y][x][c] f16. conv3x3@32: R14 weight-LDS version. ENTIRE 16x16 phase
// (pool 32->16, RCL4, RCL5, global max) fused into ONE kernel, block=image,
// A and F resident in LDS (swizzled bounce layout shared by conv reads,
// epilogue writes, and LRN ring). conv1: MFMA + fused BN-stats + pool.

#define CCH 128
constexpr float KAPPA = 0.001f / 17.0f;

typedef __attribute__((ext_vector_type(8))) _Float16 half8;
typedef __attribute__((ext_vector_type(4))) float f32x4;

union U4 { uint4 v; ushort us[8]; _Float16 h[8]; half8 f; };
union U2 { ushort4 u; _Float16 h[4]; };

// ---------------------------------------------------------------- zero stats
__global__ __launch_bounds__(256) void zero_stats(float* __restrict__ s) {
    s[threadIdx.x] = 0.f;
}

// -------------------- conv1 weight convert [128co][75] f32 -> [3kc][128co][32] f16
__global__ __launch_bounds__(256) void wcvt1(const float* __restrict__ wsrc,
                                             _Float16* __restrict__ wdst)
{
    const int idx = blockIdx.x * 256 + threadIdx.x;   // 12288
    const int kc = idx >> 12;
    const int rem = idx & 4095;
    const int co = rem >> 5;
    const int kk = rem & 31;
    const int k = kc * 32 + kk;
    wdst[idx] = (k < 75) ? (_Float16)wsrc[co * 75 + k] : (_Float16)0.f;
}

// ------------------- conv1 MFMA: stats + raw-h maxpool(3,2,1) in one kernel
__global__ __launch_bounds__(256, 2) void conv1m(
    const float* __restrict__ x, const _Float16* __restrict__ wc1,
    const float* __restrict__ bias, float* __restrict__ stats,
    _Float16* __restrict__ ph, _Float16* __restrict__ pp)
{
    __shared__ _Float16 xst[3 * 8 * 68];
    __shared__ _Float16 bnc[4 * 64 * 128];
    __shared__ float ps[4][128], ps2[4][128];

    const int bid = blockIdx.x;
    const int n = bid & 127;
    const int strip = bid >> 7;
    const int y0 = strip * 4;
    const int tid = threadIdx.x;
    const int w = tid >> 6, l = tid & 63;
    const int l15 = l & 15, lg = l >> 4;

    const float* xn = x + (size_t)n * 3 * 4096;
    for (int i = tid; i < 3 * 8 * 68; i += 256) {
        int ci = i / (8 * 68);
        int rm = i - ci * (8 * 68);
        int r = rm / 68, c = rm - r * 68;
        int gy = y0 - 2 + r, gx = c - 2;
        float v = ((unsigned)gy < 64u && (unsigned)gx < 64u)
                      ? xn[ci * 4096 + gy * 64 + gx] : 0.f;
        xst[i] = (_Float16)v;
    }

    f32x4 acc[8][4];
    #pragma unroll
    for (int cot = 0; cot < 8; ++cot) {
        f32x4 bv = *(const f32x4*)&bias[cot * 16 + lg * 4];
        #pragma unroll
        for (int pt = 0; pt < 4; ++pt) acc[cot][pt] = bv;
    }
    __syncthreads();

    #pragma unroll
    for (int kc = 0; kc < 3; ++kc) {
        int ba[8];
        #pragma unroll
        for (int j = 0; j < 8; ++j) {
            int k = kc * 32 + lg * 8 + j;
            k = k > 74 ? 74 : k;
            int ci = k / 25;
            int r = k - ci * 25;
            int ky = r / 5;
            int kx = r - ky * 5;
            ba[j] = (ci * 8 + w + ky) * 68 + l15 + kx;
        }
        half8 bf[4];
        #pragma unroll
        for (int pt = 0; pt < 4; ++pt) {
            U4 bb;
            #pragma unroll
            for (int j = 0; j < 8; ++j) bb.h[j] = xst[ba[j] + pt * 16];
            bf[pt] = bb.f;
        }
        const _Float16* wk = wc1 + kc * 4096 + l15 * 32 + lg * 8;
        #pragma unroll
        for (int cot = 0; cot < 8; ++cot) {
            half8 av = *(const half8*)&wk[cot * 512];
            #pragma unroll
            for (int pt = 0; pt < 4; ++pt)
                acc[cot][pt] = __builtin_amdgcn_mfma_f32_16x16x32_f16(
                    av, bf[pt], acc[cot][pt], 0, 0, 0);
        }
    }

    #pragma unroll
    for (int cot = 0; cot < 8; ++cot) {
        float s[4] = {0.f, 0.f, 0.f, 0.f}, s2[4] = {0.f, 0.f, 0.f, 0.f};
        #pragma unroll
        for (int pt = 0; pt < 4; ++pt)
            #pragma unroll
            for (int j = 0; j < 4; ++j) {
                float v = acc[cot][pt][j];
                s[j] += v; s2[j] += v * v;
            }
        #pragma unroll
        for (int o = 1; o < 16; o <<= 1)
            #pragma unroll
            for (int j = 0; j < 4; ++j) {
                s[j]  += __shfl_xor(s[j], o, 64);
                s2[j] += __shfl_xor(s2[j], o, 64);
            }
        if (l15 == 0) {
            #pragma unroll
            for (int j = 0; j < 4; ++j) {
                ps[w][cot * 16 + lg * 4 + j] = s[j];
                ps2[w][cot * 16 + lg * 4 + j] = s2[j];
            }
        }
    }

    #pragma unroll
    for (int cot = 0; cot < 8; ++cot)
        #pragma unroll
        for (int pt = 0; pt < 4; ++pt) {
            int c = pt * 16 + l15;
            int colx = (cot * 16 + lg * 4) ^ ((c & 7) * 8);
            U2 pk;
            pk.h[0] = (_Float16)acc[cot][pt][0];
            pk.h[1] = (_Float16)acc[cot][pt][1];
            pk.h[2] = (_Float16)acc[cot][pt][2];
            pk.h[3] = (_Float16)acc[cot][pt][3];
            *(ushort4*)&bnc[(w * 64 + c) * 128 + colx] = pk.u;
        }
    __syncthreads();

    if (tid < 128) {
        float A = ps[0][tid] + ps[1][tid] + ps[2][tid] + ps[3][tid];
        float B = ps2[0][tid] + ps2[1][tid] + ps2[2][tid] + ps2[3][tid];
        atomicAdd(&stats[tid], A);
        atomicAdd(&stats[tid + 128], B);
    }

    constexpr float NEG = -3.0e38f;
    #pragma unroll
    for (int i = 0; i < 6; ++i) {
        int t = tid + i * 256;
        if (t < 1024) {
            int cg = t & 15, ox = (t >> 4) & 31, oysel = t >> 9;
            float m[8];
            #pragma unroll
            for (int j = 0; j < 8; ++j) m[j] = NEG;
            #pragma unroll
            for (int dy = 0; dy < 3; ++dy) {
                int r = 2 * oysel - 1 + dy;
                if (r < 0) continue;
                #pragma unroll
                for (int dx = 0; dx < 3; ++dx) {
                    int c = 2 * ox - 1 + dx;
                    if ((unsigned)c >= 64u) continue;
                    U4 v;
                    v.v = *(const uint4*)&bnc[(r * 64 + c) * 128 + ((cg * 8) ^ ((c & 7) * 8))];
                    #pragma unroll
                    for (int j = 0; j < 8; ++j) m[j] = fmaxf(m[j], (float)v.h[j]);
                }
            }
            U4 o;
            #pragma unroll
            for (int j = 0; j < 8; ++j) o.h[j] = (_Float16)m[j];
            int oy = strip * 2 + oysel;
            *(uint4*)&ph[((size_t)n * 1024 + oy * 32 + ox) * 128 + cg * 8] = o.v;
        } else if (strip < 15) {
            int t2 = t - 1024;
            int cg = t2 & 15, ox = (t2 >> 4) & 31;
            float m[8];
            #pragma unroll
            for (int j = 0; j < 8; ++j) m[j] = NEG;
            #pragma unroll
            for (int dx = 0; dx < 3; ++dx) {
                int c = 2 * ox - 1 + dx;
                if ((unsigned)c >= 64u) continue;
                U4 v;
                v.v = *(const uint4*)&bnc[(3 * 64 + c) * 128 + ((cg * 8) ^ ((c & 7) * 8))];
                #pragma unroll
                for (int j = 0; j < 8; ++j) m[j] = fmaxf(m[j], (float)v.h[j]);
            }
            U4 o;
            #pragma unroll
            for (int j = 0; j < 8; ++j) o.h[j] = (_Float16)m[j];
            *(uint4*)&pp[(((size_t)n * 15 + strip) * 32 + ox) * 128 + cg * 8] = o.v;
        }
    }
}

// ------------- merge halo partials into pooled rows oy = 2s+2 (s=0..14)
__global__ __launch_bounds__(256) void pool_fixr(const _Float16* __restrict__ pp,
                                                 _Float16* __restrict__ ph)
{
    const int idx = blockIdx.x * 256 + threadIdx.x;   // 983040
    const int cg = idx & 15;
    const int ox = (idx >> 4) & 31;
    const int t = idx >> 9;
    const int s = t % 15;
    const int n = t / 15;
    const _Float16* p = pp + (((size_t)n * 15 + s) * 32 + ox) * 128 + cg * 8;
    _Float16* a = ph + ((size_t)n * 1024 + (2 * s + 2) * 32 + ox) * 128 + cg * 8;
    U4 av, bv;
    av.v = *(const uint4*)a;
    bv.v = *(const uint4*)p;
    #pragma unroll
    for (int j = 0; j < 8; ++j)
        if ((float)bv.h[j] > (float)av.h[j]) av.h[j] = bv.h[j];
    *(uint4*)a = av.v;
}

// --------------------------------------------------------------- bn finalize
__global__ __launch_bounds__(128) void bn_finalize(
    const float* __restrict__ stats, const float* __restrict__ g,
    const float* __restrict__ b, float* __restrict__ scsh)
{
    const int c = threadIdx.x;
    const float M = 128.f * 4096.f;
    float mean = stats[c] / M;
    float var = stats[c + 128] / M - mean * mean;
    float rstd = rsqrtf(var + 1e-5f);
    float sc = g[c] * rstd;
    scsh[c] = sc;
    scsh[c + 128] = b[c] - mean * sc;
}

// ------------------- BN + relu applied to pooled raw h (valid: scale > 0)
__global__ __launch_bounds__(256) void bnrelu(
    const _Float16* __restrict__ ph, const float* __restrict__ scsh,
    _Float16* __restrict__ out)
{
    const int idx = blockIdx.x * 256 + threadIdx.x;   // 2097152
    const int cg = idx & 15;
    const size_t e = (size_t)(idx >> 4) * 128 + cg * 8;
    U4 v; v.v = *(const uint4*)&ph[e];
    U4 o;
    #pragma unroll
    for (int j = 0; j < 8; ++j) {
        int co = cg * 8 + j;
        float f = (float)v.h[j] * scsh[co] + scsh[co + 128];
        o.h[j] = (_Float16)fmaxf(f, 0.f);
    }
    *(uint4*)&out[e] = o.v;
}

// --------------------------------------- weight convert fp32 [co][ci][3][3]
//                                      -> f16 [tap][co][ci]
__global__ __launch_bounds__(256) void wcvt(const float* __restrict__ wsrc,
                                            _Float16* __restrict__ wdst)
{
    const int idx = blockIdx.x * 256 + threadIdx.x;   // 147456
    const int t = idx >> 14;
    const int rem = idx & 16383;
    const int co = rem >> 7;
    const int ci = rem & 127;
    wdst[idx] = (_Float16)wsrc[(co * 128 + ci) * 9 + t];
}

// ------------------------ conv3x3 MFMA @32 (128->128, pad 1) + FUSED LRN
// R14: 8-row strips, 4 waves, weights staged in LDS (pad-40 rows), fused
// banded-LRN epilogue. Grid 512, LDS 119KB, 1 block/CU.
template<bool ADD_F>
__global__ __launch_bounds__(256, 1) void conv3f(
    const _Float16* __restrict__ in, const _Float16* __restrict__ wb,
    const float* __restrict__ bias, _Float16* __restrict__ fbuf,
    _Float16* __restrict__ outp)
{
    constexpr int W = 32, HW = 1024;
    constexpr int XP = 34;
    constexpr int PITCH = 40;
    constexpr int ROWS = 10;
    constexpr int PTN = 4;
    constexpr int NPIX = 64;
    constexpr int WROW = 40;
    constexpr int WOFF = 9 * 128 * WROW;
    constexpr int STAGE = ROWS * XP * PITCH;
    constexpr int TASKS = ROWS * W * 4;
    constexpr int NIT = 5;
    constexpr int WNIT = 18;
    constexpr int LOG4W = 7;
    constexpr int LDSH = WOFF + STAGE;

    __shared__ _Float16 xs[LDSH];

    const int bid = blockIdx.x;
    const int slot = bid >> 3;
    const int n = (bid & 7) + 8 * (slot & 15);
    const int y0 = (slot >> 4) * 8;
    const int tid = threadIdx.x;
    const int w = tid >> 6, l = tid & 63;
    const int l15 = l & 15, lg = l >> 4;

    for (int i = tid; i < STAGE / 2; i += 256) ((uint*)(xs + WOFF))[i] = 0;

    f32x4 acc[8][PTN];
    #pragma unroll
    for (int cot = 0; cot < 8; ++cot) {
        f32x4 bv = {0.f, 0.f, 0.f, 0.f};
        if constexpr (!ADD_F) bv = *(const f32x4*)&bias[cot * 16 + lg * 4];
        #pragma unroll
        for (int pt = 0; pt < PTN; ++pt) acc[cot][pt] = bv;
    }

    const _Float16* inb = in + (size_t)n * HW * 128;
    uint4 stg[NIT];
    uint4 wreg[WNIT];

    auto issue = [&](int c0) {
        #pragma unroll
        for (int i = 0; i < NIT; ++i) {
            int t = tid + i * 256;
            uint4 v = {0u, 0u, 0u, 0u};
            {
                int g = t & 3, xx = (t >> 2) & (W - 1), yl = t >> LOG4W;
                int gy = y0 - 1 + yl;
                if ((unsigned)gy < (unsigned)W)
                    v = *(const uint4*)&inb[((size_t)(gy * W + xx)) * 128 + c0 + g * 8];
            }
            stg[i] = v;
        }
    };
    auto commit = [&]() {
        #pragma unroll
        for (int i = 0; i < NIT; ++i) {
            int t = tid + i * 256;
            int g = t & 3, xx = (t >> 2) & (W - 1), yl = t >> LOG4W;
            *(uint4*)&xs[WOFF + (yl * XP + xx + 1) * PITCH + g * 8] = stg[i];
        }
    };
    auto wissue = [&](int c0) {
        #pragma unroll
        for (int i = 0; i < WNIT; ++i) {
            int tsk = tid + i * 256;
            int g = tsk & 3, co = (tsk >> 2) & 127, tp = tsk >> 9;
            wreg[i] = *(const uint4*)&wb[tp * 16384 + co * 128 + c0 + g * 8];
        }
    };
    auto wcommit = [&]() {
        #pragma unroll
        for (int i = 0; i < WNIT; ++i) {
            int tsk = tid + i * 256;
            int g = tsk & 3, co = (tsk >> 2) & 127, tp = tsk >> 9;
            *(uint4*)&xs[(tp * 128 + co) * WROW + g * 8] = wreg[i];
        }
    };

    int bofs[PTN];
    #pragma unroll
    for (int pt = 0; pt < PTN; ++pt) {
        int row_l = 2 * w + (pt >> 1);
        int xb = (pt & 1) * 16 + l15;
        bofs[pt] = WOFF + ((row_l + 1) * XP + xb + 1) * PITCH + lg * 8;
    }
    const int wlane = l15 * WROW + lg * 8;

    issue(0);
    wissue(0);
    __syncthreads();
    commit();
    wcommit();
    issue(32);
    wissue(32);
    __syncthreads();

    for (int cc = 0; cc < 4; ++cc) {
        #pragma unroll
        for (int ky = -1; ky <= 1; ++ky)
            #pragma unroll
            for (int kx = -1; kx <= 1; ++kx) {
                const int t9 = (ky + 1) * 3 + (kx + 1);
                half8 bf[PTN];
                #pragma unroll
                for (int pt = 0; pt < PTN; ++pt)
                    bf[pt] = *(const half8*)&xs[bofs[pt] + (ky * XP + kx) * PITCH];
                const int wbase = t9 * (128 * WROW) + wlane;
                #pragma unroll
                for (int coh = 0; coh < 2; ++coh) {
                    half8 av[4];
                    #pragma unroll
                    for (int j = 0; j < 4; ++j)
                        av[j] = *(const half8*)&xs[wbase + (coh * 4 + j) * (16 * WROW)];
                    #pragma unroll
                    for (int j = 0; j < 4; ++j)
                        #pragma unroll
                        for (int pt = 0; pt < PTN; ++pt)
                            acc[coh * 4 + j][pt] = __builtin_amdgcn_mfma_f32_16x16x32_f16(
                                av[j], bf[pt], acc[coh * 4 + j][pt], 0, 0, 0);
                }
            }
        if (cc < 3) {
            __syncthreads();
            commit();
            wcommit();
            if (cc < 2) { issue((cc + 2) * 32); wissue((cc + 2) * 32); }
            __syncthreads();
        }
    }

    __syncthreads();
    _Float16* bx = xs + w * (NPIX * 128);
    #pragma unroll
    for (int a = 0; a < 8; ++a)
        #pragma unroll
        for (int pt = 0; pt < PTN; ++pt) {
            const int wpx = pt * 16 + l15;
            const int col = (a * 16 + lg * 4) ^ ((wpx & 7) * 8);
            U2 pk;
            pk.h[0] = (_Float16)acc[a][pt][0];
            pk.h[1] = (_Float16)acc[a][pt][1];
            pk.h[2] = (_Float16)acc[a][pt][2];
            pk.h[3] = (_Float16)acc[a][pt][3];
            *(ushort4*)&bx[wpx * 128 + col] = pk.u;
        }
    __syncthreads();

    {
        const int px = l;
        const int p3 = px & 7;
        U4 sv[16];
        #pragma unroll
        for (int g = 0; g < 16; ++g)
            sv[g].v = *(const uint4*)&bx[px * 128 + ((g ^ p3) * 8)];

        const int row_l = 2 * w + (px >> 5);
        const int xo = px & (W - 1);
        const size_t gbase = ((size_t)n * HW + (size_t)(y0 + row_l) * W + xo) * 128;

        if constexpr (ADD_F) {
            #pragma unroll
            for (int g = 0; g < 16; ++g) {
                U4 fv; fv.v = *(const uint4*)&fbuf[gbase + g * 8];
                #pragma unroll
                for (int j = 0; j < 8; ++j)
                    sv[g].h[j] = (_Float16)((float)sv[g].h[j] + (float)fv.h[j]);
            }
        } else {
            #pragma unroll
            for (int g = 0; g < 16; ++g)
                *(uint4*)&fbuf[gbase + g * 8] = sv[g].v;
        }

        float ring[17], zr[9], wsum = 0.f;
        #pragma unroll
        for (int i = 0; i < 17; ++i) ring[i] = 0.f;
        #pragma unroll
        for (int i = 0; i < 9; ++i) zr[i] = 0.f;
        U4 ob;
        #pragma unroll
        for (int c = 0; c < 136; ++c) {
            float z = 0.f;
            if (c < 128) {
                float v = (float)sv[c >> 3].h[c & 7];
                z = v > 0.f ? v : 0.f;
            }
            float zz = z * z;
            wsum += zz - ring[c % 17];
            ring[c % 17] = zz;
            zr[c % 9] = z;
            if (c >= 8) {
                int o = c - 8;
                float p75 = exp2f(-0.75f * log2f(wsum * KAPPA + 1.f));
                ob.h[o & 7] = (_Float16)(zr[(c + 1) % 9] * p75);
                if ((o & 7) == 7) *(uint4*)&outp[gbase + (o & ~7)] = ob.v;
            }
        }
    }
}

// ==================== FUSED 16x16 phase: pool + RCL4 + RCL5 + global max
// Block = 1 image, 512 threads (8 waves). A,F resident in LDS (swizzled
// [px][ch ^ (px&7)*8] layout used by conv reads, epilogue, LRN, gmax).
// Wave w owns rows {2w, 2w+1}; per conv: acc[8co-tiles][2px-tiles].
__global__ __launch_bounds__(512, 1) void rcl16(
    const _Float16* __restrict__ a32, const _Float16* __restrict__ wbl,
    const float* __restrict__ fb4, const float* __restrict__ fb5,
    float* __restrict__ gm)
{
    __shared__ _Float16 Al[256 * 128];   // 64 KB
    __shared__ _Float16 Fl[256 * 128];   // 64 KB
    __shared__ float psm[4][128];

    const int n = blockIdx.x;
    const int tid = threadIdx.x;
    const int w = tid >> 6, l = tid & 63;
    const int l15 = l & 15, lg = l >> 4;
    const half8 zero8 = {(_Float16)0, (_Float16)0, (_Float16)0, (_Float16)0,
                         (_Float16)0, (_Float16)0, (_Float16)0, (_Float16)0};

    // ---- pool 32x32 -> 16x16 (maxpool 3,2,1; inputs >= 0) into Al
    const _Float16* ib = a32 + (size_t)n * 1024 * 128;
    #pragma unroll
    for (int i = 0; i < 8; ++i) {
        int t = tid + i * 512;            // 4096 tasks
        int cg = t & 15, opix = t >> 4;
        int oy = opix >> 4, ox = opix & 15;
        float m[8] = {0.f, 0.f, 0.f, 0.f, 0.f, 0.f, 0.f, 0.f};
        #pragma unroll
        for (int dy = -1; dy <= 1; ++dy) {
            int iy = 2 * oy + dy;
            if ((unsigned)iy >= 32u) continue;
            #pragma unroll
            for (int dx = -1; dx <= 1; ++dx) {
                int ix = 2 * ox + dx;
                if ((unsigned)ix >= 32u) continue;
                U4 v; v.v = *(const uint4*)&ib[(size_t)(iy * 32 + ix) * 128 + cg * 8];
                #pragma unroll
                for (int j = 0; j < 8; ++j) m[j] = fmaxf(m[j], (float)v.h[j]);
            }
        }
        U4 o;
        #pragma unroll
        for (int j = 0; j < 8; ++j) o.h[j] = (_Float16)m[j];
        *(uint4*)&Al[opix * 128 + ((cg * 8) ^ ((opix & 7) * 8))] = o.v;
    }
    __syncthreads();

    // ---- 2 stages x 4 iterations, all in LDS
    for (int s = 0; s < 2; ++s) {
        const float* bias = s ? fb5 : fb4;
        for (int it = 0; it < 4; ++it) {
            const _Float16* wlay = wbl + (size_t)(2 * s + (it ? 1 : 0)) * 147456;
            const _Float16* wl = wlay + l15 * 128 + lg * 8;

            f32x4 acc[8][2];
            #pragma unroll
            for (int a = 0; a < 8; ++a) {
                f32x4 bv = {0.f, 0.f, 0.f, 0.f};
                if (it == 0) bv = *(const f32x4*)&bias[a * 16 + lg * 4];
                acc[a][0] = bv; acc[a][1] = bv;
            }

            for (int c0 = 0; c0 < 128; c0 += 32) {
                #pragma unroll
                for (int ky = -1; ky <= 1; ++ky)
                    #pragma unroll
                    for (int kx = -1; kx <= 1; ++kx) {
                        const int t9 = (ky + 1) * 3 + (kx + 1);
                        half8 bf[2];
                        #pragma unroll
                        for (int pt = 0; pt < 2; ++pt) {
                            int row = 2 * w + pt;
                            int r2 = row + ky, x2 = l15 + kx;
                            bool ok = (unsigned)r2 < 16u && (unsigned)x2 < 16u;
                            int rpx = ok ? (r2 * 16 + x2) : (row * 16 + l15);
                            half8 v = *(const half8*)&Al[rpx * 128 +
                                          ((c0 + lg * 8) ^ ((rpx & 7) * 8))];
                            bf[pt] = ok ? v : zero8;
                        }
                        const _Float16* wt = wl + t9 * 16384 + c0;
                        #pragma unroll
                        for (int coh = 0; coh < 2; ++coh) {
                            half8 av[4];
                            #pragma unroll
                            for (int j = 0; j < 4; ++j)
                                av[j] = *(const half8*)&wt[(coh * 4 + j) * 2048];
                            #pragma unroll
                            for (int j = 0; j < 4; ++j)
                                #pragma unroll
                                for (int pt = 0; pt < 2; ++pt)
                                    acc[coh * 4 + j][pt] =
                                        __builtin_amdgcn_mfma_f32_16x16x32_f16(
                                            av[j], bf[pt], acc[coh * 4 + j][pt], 0, 0, 0);
                        }
                    }
            }
            __syncthreads();               // all conv reads of Al done

            // combine: s = f (save) or f + conv(r); write to Al (and Fl)
            #pragma unroll
            for (int a = 0; a < 8; ++a)
                #pragma unroll
                for (int pt = 0; pt < 2; ++pt) {
                    int px = (2 * w + pt) * 16 + l15;
                    int col = (a * 16 + lg * 4) ^ ((px & 7) * 8);
                    U2 pk;
                    if (it == 0) {
                        pk.h[0] = (_Float16)acc[a][pt][0];
                        pk.h[1] = (_Float16)acc[a][pt][1];
                        pk.h[2] = (_Float16)acc[a][pt][2];
                        pk.h[3] = (_Float16)acc[a][pt][3];
                        *(ushort4*)&Fl[px * 128 + col] = pk.u;
                    } else {
                        U2 cur; cur.u = *(const ushort4*)&Fl[px * 128 + col];
                        pk.h[0] = (_Float16)(acc[a][pt][0] + (float)cur.h[0]);
                        pk.h[1] = (_Float16)(acc[a][pt][1] + (float)cur.h[1]);
                        pk.h[2] = (_Float16)(acc[a][pt][2] + (float)cur.h[2]);
                        pk.h[3] = (_Float16)(acc[a][pt][3] + (float)cur.h[3]);
                    }
                    *(ushort4*)&Al[px * 128 + col] = pk.u;
                }
            __syncthreads();

            // segmented LRN ring (NSUB=2, SEGO=64): in-place on Al
            {
                const int px = tid & 255;
                const int seg = tid >> 8;
                const int p3 = px & 7;
                const int cstart = seg ? 56 : 0;
                const int gb0 = cstart >> 3;
                const int zlim = 128 - cstart;
                const int wlo = seg ? 16 : 8;
                const int whi = wlo + 64;

                U4 sv[10];
                #pragma unroll
                for (int i = 0; i < 10; ++i) {
                    int g = gb0 + i; g = g > 15 ? 15 : g;
                    sv[i].v = *(const uint4*)&Al[px * 128 + ((g ^ p3) * 8)];
                }
                __syncthreads();           // all reads done before writes

                float ring[17], zr[9], wsum = 0.f;
                #pragma unroll
                for (int i = 0; i < 17; ++i) ring[i] = 0.f;
                #pragma unroll
                for (int i = 0; i < 9; ++i) zr[i] = 0.f;
                U4 ob;
                #pragma unroll
                for (int cl = 0; cl < 80; ++cl) {
                    float v = (float)sv[cl >> 3].h[cl & 7];
                    float z = (cl < zlim && v > 0.f) ? v : 0.f;
                    float zz = z * z;
                    wsum += zz - ring[cl % 17];
                    ring[cl % 17] = zz;
                    zr[cl % 9] = z;
                    if (cl >= 8) {
                        const int q = (cl - 8) & 7;
                        float p75 = exp2f(-0.75f * log2f(wsum * KAPPA + 1.f));
                        ob.h[q] = (_Float16)(zr[(cl + 1) % 9] * p75);
                        if (q == 7 && cl >= wlo && cl < whi) {
                            const int o7 = cstart + cl - 15;
                            *(uint4*)&Al[px * 128 + (((o7 >> 3) ^ p3) * 8)] = ob.v;
                        }
                    }
                }
            }
            __syncthreads();
        }
    }

    // ---- global max over [0,15)x[0,15) per channel
    {
        int c = tid & 127, q = tid >> 7;
        float m = 0.f;
        for (int p = q * 64; p < q * 64 + 64; ++p) {
            int py = p >> 4, pxx = p & 15;
            if (py < 15 && pxx < 15)
                m = fmaxf(m, (float)Al[p * 128 + (c ^ ((p & 7) * 8))]);
        }
        psm[q][c] = m;
        __syncthreads();
        if (tid < 128)
            gm[n * 128 + tid] = fmaxf(fmaxf(psm[0][tid], psm[1][tid]),
                                      fmaxf(psm[2][tid], psm[3][tid]));
    }
}

// ------------------------------------------------------------------- MLP
__global__ __launch_bounds__(256) void mlp_k(
    const float* __restrict__ g, const float* __restrict__ w,
    const float* __restrict__ b, float* __restrict__ out)
{
    const int idx = blockIdx.x * 256 + threadIdx.x;
    if (idx >= 1280) return;
    const int n = idx / 10, k = idx - n * 10;
    float acc = b[k];
    for (int c = 0; c < CCH; ++c) acc += g[n * CCH + c] * w[k * CCH + c];
    out[idx] = acc;
}

// ==================================================================== launch
extern "C" void kernel_launch(void* const* d_in, const int* in_sizes, int n_in,
                              void* d_out, int out_size, void* d_ws, size_t ws_size,
                              hipStream_t stream)
{
    const float* x   = (const float*)d_in[0];
    const float* w1  = (const float*)d_in[1];
    const float* b1  = (const float*)d_in[2];
    const float* bng = (const float*)d_in[3];
    const float* bnb = (const float*)d_in[4];
    const float* fw[4] = {(const float*)d_in[5],  (const float*)d_in[8],
                          (const float*)d_in[11], (const float*)d_in[14]};
    const float* fb[4] = {(const float*)d_in[6],  (const float*)d_in[9],
                          (const float*)d_in[12], (const float*)d_in[15]};
    const float* rw[4] = {(const float*)d_in[7],  (const float*)d_in[10],
                          (const float*)d_in[13], (const float*)d_in[16]};
    const float* mw = (const float*)d_in[17];
    const float* mb = (const float*)d_in[18];
    float* out = (float*)d_out;

    _Float16* ws16 = (_Float16*)d_ws;
    _Float16* buf0 = ws16;                       // [128][1024][128] ping
    _Float16* buf1 = ws16 + 16777216;            // pong; also PH
    _Float16* Fb32 = ws16 + 2 * 16777216;        // f persistence (32x32)
    _Float16* base3 = ws16 + 3 * 16777216;
    _Float16* Wb   = base3 + 3 * 4194304;        // 8 x [9][128][128]
    float* stats = (float*)(Wb + 8 * 147456);
    float* scsh  = stats + 256;
    float* gm    = scsh + 256;
    _Float16* Pp  = (_Float16*)(gm + 16384);     // [128][15][32][128] halo max
    _Float16* Wc1 = Pp + 7864320;                // [3][128][32]
    _Float16* PH  = buf1;

    zero_stats<<<1, 256, 0, stream>>>(stats);
    wcvt1<<<48, 256, 0, stream>>>(w1, Wc1);
    conv1m<<<2048, 256, 0, stream>>>(x, Wc1, b1, stats, PH, Pp);
    pool_fixr<<<3840, 256, 0, stream>>>(Pp, PH);
    bn_finalize<<<1, 128, 0, stream>>>(stats, bng, bnb, scsh);
    bnrelu<<<8192, 256, 0, stream>>>(PH, scsh, buf0);

    const float* lw[8] = {fw[0], rw[0], fw[1], rw[1], fw[2], rw[2], fw[3], rw[3]};
    for (int i = 0; i < 8; ++i)
        wcvt<<<576, 256, 0, stream>>>(lw[i], Wb + i * 147456);

    _Float16* cur = buf0;
    _Float16* alt = buf1;
    for (int s = 0; s < 2; ++s) {
        conv3f<false><<<512, 256, 0, stream>>>(cur, Wb + (2*s) * 147456, fb[s], Fb32, alt);
        { _Float16* t = cur; cur = alt; alt = t; }
        for (int it = 0; it < 3; ++it) {
            conv3f<true><<<512, 256, 0, stream>>>(cur, Wb + (2*s+1) * 147456, nullptr, Fb32, alt);
            { _Float16* t = cur; cur = alt; alt = t; }
        }
    }
    // 8 swaps -> cur == buf0

    rcl16<<<128, 512, 0, stream>>>(cur, Wb + 4 * 147456, fb[2], fb[3], gm);
    mlp_k<<<5, 256, 0, stream>>>(gm, mw, mb, out);
}

// Round 16
// 1299.125 us; speedup vs baseline: 1.1480x; 1.1480x over previous
//
#include <hip/hip_runtime.h>

// RCNN forward. ALL convs on MFMA f16 (implicit GEMM); activations
// [n][y][x][c] f16. conv3x3: R14 geometry — 8-row strips, 4 waves, weights
// staged in LDS (pad-40 rows), fused banded-LRN epilogue. First conv3f also
// applies conv1's BN+relu during stage-in (DO_BN), removing the bnrelu pass.
// conv1 (5x5,3->128): MFMA K=75->3x32, fused BN-stats + raw-h maxpool.

#define CCH 128
constexpr float KAPPA = 0.001f / 17.0f;

typedef __attribute__((ext_vector_type(8))) _Float16 half8;
typedef __attribute__((ext_vector_type(4))) float f32x4;

union U4 { uint4 v; ushort us[8]; _Float16 h[8]; half8 f; };
union U2 { ushort4 u; _Float16 h[4]; };

// ---------------------------------------------------------------- zero stats
__global__ __launch_bounds__(256) void zero_stats(float* __restrict__ s) {
    s[threadIdx.x] = 0.f;
}

// -------------------- conv1 weight convert [128co][75] f32 -> [3kc][128co][32] f16
__global__ __launch_bounds__(256) void wcvt1(const float* __restrict__ wsrc,
                                             _Float16* __restrict__ wdst)
{
    const int idx = blockIdx.x * 256 + threadIdx.x;   // 12288
    const int kc = idx >> 12;
    const int rem = idx & 4095;
    const int co = rem >> 5;
    const int kk = rem & 31;
    const int k = kc * 32 + kk;
    wdst[idx] = (k < 75) ? (_Float16)wsrc[co * 75 + k] : (_Float16)0.f;
}

// ------------------- conv1 MFMA: stats + raw-h maxpool(3,2,1) in one kernel
__global__ __launch_bounds__(256, 2) void conv1m(
    const float* __restrict__ x, const _Float16* __restrict__ wc1,
    const float* __restrict__ bias, float* __restrict__ stats,
    _Float16* __restrict__ ph, _Float16* __restrict__ pp)
{
    __shared__ _Float16 xst[3 * 8 * 68];
    __shared__ _Float16 bnc[4 * 64 * 128];
    __shared__ float ps[4][128], ps2[4][128];

    const int bid = blockIdx.x;
    const int n = bid & 127;
    const int strip = bid >> 7;
    const int y0 = strip * 4;
    const int tid = threadIdx.x;
    const int w = tid >> 6, l = tid & 63;
    const int l15 = l & 15, lg = l >> 4;

    const float* xn = x + (size_t)n * 3 * 4096;
    for (int i = tid; i < 3 * 8 * 68; i += 256) {
        int ci = i / (8 * 68);
        int rm = i - ci * (8 * 68);
        int r = rm / 68, c = rm - r * 68;
        int gy = y0 - 2 + r, gx = c - 2;
        float v = ((unsigned)gy < 64u && (unsigned)gx < 64u)
                      ? xn[ci * 4096 + gy * 64 + gx] : 0.f;
        xst[i] = (_Float16)v;
    }

    f32x4 acc[8][4];
    #pragma unroll
    for (int cot = 0; cot < 8; ++cot) {
        f32x4 bv = *(const f32x4*)&bias[cot * 16 + lg * 4];
        #pragma unroll
        for (int pt = 0; pt < 4; ++pt) acc[cot][pt] = bv;
    }
    __syncthreads();

    #pragma unroll
    for (int kc = 0; kc < 3; ++kc) {
        int ba[8];
        #pragma unroll
        for (int j = 0; j < 8; ++j) {
            int k = kc * 32 + lg * 8 + j;
            k = k > 74 ? 74 : k;
            int ci = k / 25;
            int r = k - ci * 25;
            int ky = r / 5;
            int kx = r - ky * 5;
            ba[j] = (ci * 8 + w + ky) * 68 + l15 + kx;
        }
        half8 bf[4];
        #pragma unroll
        for (int pt = 0; pt < 4; ++pt) {
            U4 bb;
            #pragma unroll
            for (int j = 0; j < 8; ++j) bb.h[j] = xst[ba[j] + pt * 16];
            bf[pt] = bb.f;
        }
        const _Float16* wk = wc1 + kc * 4096 + l15 * 32 + lg * 8;
        #pragma unroll
        for (int cot = 0; cot < 8; ++cot) {
            half8 av = *(const half8*)&wk[cot * 512];
            #pragma unroll
            for (int pt = 0; pt < 4; ++pt)
                acc[cot][pt] = __builtin_amdgcn_mfma_f32_16x16x32_f16(
                    av, bf[pt], acc[cot][pt], 0, 0, 0);
        }
    }

    #pragma unroll
    for (int cot = 0; cot < 8; ++cot) {
        float s[4] = {0.f, 0.f, 0.f, 0.f}, s2[4] = {0.f, 0.f, 0.f, 0.f};
        #pragma unroll
        for (int pt = 0; pt < 4; ++pt)
            #pragma unroll
            for (int j = 0; j < 4; ++j) {
                float v = acc[cot][pt][j];
                s[j] += v; s2[j] += v * v;
            }
        #pragma unroll
        for (int o = 1; o < 16; o <<= 1)
            #pragma unroll
            for (int j = 0; j < 4; ++j) {
                s[j]  += __shfl_xor(s[j], o, 64);
                s2[j] += __shfl_xor(s2[j], o, 64);
            }
        if (l15 == 0) {
            #pragma unroll
            for (int j = 0; j < 4; ++j) {
                ps[w][cot * 16 + lg * 4 + j] = s[j];
                ps2[w][cot * 16 + lg * 4 + j] = s2[j];
            }
        }
    }

    #pragma unroll
    for (int cot = 0; cot < 8; ++cot)
        #pragma unroll
        for (int pt = 0; pt < 4; ++pt) {
            int c = pt * 16 + l15;
            int colx = (cot * 16 + lg * 4) ^ ((c & 7) * 8);
            U2 pk;
            pk.h[0] = (_Float16)acc[cot][pt][0];
            pk.h[1] = (_Float16)acc[cot][pt][1];
            pk.h[2] = (_Float16)acc[cot][pt][2];
            pk.h[3] = (_Float16)acc[cot][pt][3];
            *(ushort4*)&bnc[(w * 64 + c) * 128 + colx] = pk.u;
        }
    __syncthreads();

    if (tid < 128) {
        float A = ps[0][tid] + ps[1][tid] + ps[2][tid] + ps[3][tid];
        float B = ps2[0][tid] + ps2[1][tid] + ps2[2][tid] + ps2[3][tid];
        atomicAdd(&stats[tid], A);
        atomicAdd(&stats[tid + 128], B);
    }

    constexpr float NEG = -3.0e38f;
    #pragma unroll
    for (int i = 0; i < 6; ++i) {
        int t = tid + i * 256;
        if (t < 1024) {
            int cg = t & 15, ox = (t >> 4) & 31, oysel = t >> 9;
            float m[8];
            #pragma unroll
            for (int j = 0; j < 8; ++j) m[j] = NEG;
            #pragma unroll
            for (int dy = 0; dy < 3; ++dy) {
                int r = 2 * oysel - 1 + dy;
                if (r < 0) continue;
                #pragma unroll
                for (int dx = 0; dx < 3; ++dx) {
                    int c = 2 * ox - 1 + dx;
                    if ((unsigned)c >= 64u) continue;
                    U4 v;
                    v.v = *(const uint4*)&bnc[(r * 64 + c) * 128 + ((cg * 8) ^ ((c & 7) * 8))];
                    #pragma unroll
                    for (int j = 0; j < 8; ++j) m[j] = fmaxf(m[j], (float)v.h[j]);
                }
            }
            U4 o;
            #pragma unroll
            for (int j = 0; j < 8; ++j) o.h[j] = (_Float16)m[j];
            int oy = strip * 2 + oysel;
            *(uint4*)&ph[((size_t)n * 1024 + oy * 32 + ox) * 128 + cg * 8] = o.v;
        } else if (strip < 15) {
            int t2 = t - 1024;
            int cg = t2 & 15, ox = (t2 >> 4) & 31;
            float m[8];
            #pragma unroll
            for (int j = 0; j < 8; ++j) m[j] = NEG;
            #pragma unroll
            for (int dx = 0; dx < 3; ++dx) {
                int c = 2 * ox - 1 + dx;
                if ((unsigned)c >= 64u) continue;
                U4 v;
                v.v = *(const uint4*)&bnc[(3 * 64 + c) * 128 + ((cg * 8) ^ ((c & 7) * 8))];
                #pragma unroll
                for (int j = 0; j < 8; ++j) m[j] = fmaxf(m[j], (float)v.h[j]);
            }
            U4 o;
            #pragma unroll
            for (int j = 0; j < 8; ++j) o.h[j] = (_Float16)m[j];
            *(uint4*)&pp[(((size_t)n * 15 + strip) * 32 + ox) * 128 + cg * 8] = o.v;
        }
    }
}

// ------------- merge halo partials into pooled rows oy = 2s+2 (s=0..14)
__global__ __launch_bounds__(256) void pool_fixr(const _Float16* __restrict__ pp,
                                                 _Float16* __restrict__ ph)
{
    const int idx = blockIdx.x * 256 + threadIdx.x;   // 983040
    const int cg = idx & 15;
    const int ox = (idx >> 4) & 31;
    const int t = idx >> 9;
    const int s = t % 15;
    const int n = t / 15;
    const _Float16* p = pp + (((size_t)n * 15 + s) * 32 + ox) * 128 + cg * 8;
    _Float16* a = ph + ((size_t)n * 1024 + (2 * s + 2) * 32 + ox) * 128 + cg * 8;
    U4 av, bv;
    av.v = *(const uint4*)a;
    bv.v = *(const uint4*)p;
    #pragma unroll
    for (int j = 0; j < 8; ++j)
        if ((float)bv.h[j] > (float)av.h[j]) av.h[j] = bv.h[j];
    *(uint4*)a = av.v;
}

// --------------------------------------------------------------- bn finalize
__global__ __launch_bounds__(128) void bn_finalize(
    const float* __restrict__ stats, const float* __restrict__ g,
    const float* __restrict__ b, float* __restrict__ scsh)
{
    const int c = threadIdx.x;
    const float M = 128.f * 4096.f;
    float mean = stats[c] / M;
    float var = stats[c + 128] / M - mean * mean;
    float rstd = rsqrtf(var + 1e-5f);
    float sc = g[c] * rstd;
    scsh[c] = sc;
    scsh[c + 128] = b[c] - mean * sc;
}

// --------------------------------------- weight convert fp32 [co][ci][3][3]
//                                      -> f16 [tap][co][ci]
__global__ __launch_bounds__(256) void wcvt(const float* __restrict__ wsrc,
                                            _Float16* __restrict__ wdst)
{
    const int idx = blockIdx.x * 256 + threadIdx.x;   // 147456
    const int t = idx >> 14;
    const int rem = idx & 16383;
    const int co = rem >> 7;
    const int ci = rem & 127;
    wdst[idx] = (_Float16)wsrc[(co * 128 + ci) * 9 + t];
}

// ------------------------ conv3x3 MFMA (128->128, pad 1) + FUSED banded LRN
// R14: 8-row strips, 4 waves; wave = 2 rows x W px, all 128 co. Weights in
// LDS (pad-40 rows, reg-prefetched one chunk ahead). DO_BN: apply conv1's
// BN+relu per staged element (first dispatch only; input = pooled raw h).
// Epilogue: per-wave swizzled bounce -> per-lane LRN ring -> scattered I/O.
// H=32: grid 512, LDS 119KB; H=16: grid 256, LDS 107KB. 1 block/CU.
template<int H, bool ADD_F, bool DO_BN>
__global__ __launch_bounds__(256, 1) void conv3f(
    const _Float16* __restrict__ in, const _Float16* __restrict__ wb,
    const float* __restrict__ bias, const float* __restrict__ scsh,
    _Float16* __restrict__ fbuf, _Float16* __restrict__ outp)
{
    constexpr int W = H, HW = H * W;
    constexpr int XP = W + 2;
    constexpr int PITCH = 40;                  // x-stage f16 per pixel slot
    constexpr int ROWS = 10;
    constexpr int PTN = (H == 32) ? 4 : 2;
    constexpr int NPIX = PTN * 16;
    constexpr int WROW = 40;                   // weight LDS row (f16), 80B
    constexpr int WOFF = 9 * 128 * WROW;       // 46080 f16 weight region
    constexpr int STAGE = ROWS * XP * PITCH;   // 13600 / 7200 f16
    constexpr int TASKS = ROWS * W * 4;
    constexpr int NIT = (TASKS + 255) / 256;
    constexpr int WNIT = 18;                   // 4608 weight uint4 / 256 thr
    constexpr int LOG4W = (H == 32) ? 7 : 6;
    constexpr int LDSH = WOFF + STAGE;

    __shared__ _Float16 xs[LDSH];

    const int bid = blockIdx.x;
    const int slot = bid >> 3;
    const int n = (bid & 7) + 8 * (slot & 15);
    const int y0 = (slot >> 4) * 8;
    const int tid = threadIdx.x;
    const int w = tid >> 6, l = tid & 63;
    const int l15 = l & 15, lg = l >> 4;

    for (int i = tid; i < STAGE / 2; i += 256) ((uint*)(xs + WOFF))[i] = 0;

    f32x4 acc[8][PTN];
    #pragma unroll
    for (int cot = 0; cot < 8; ++cot) {
        f32x4 bv = {0.f, 0.f, 0.f, 0.f};
        if constexpr (!ADD_F) bv = *(const f32x4*)&bias[cot * 16 + lg * 4];
        #pragma unroll
        for (int pt = 0; pt < PTN; ++pt) acc[cot][pt] = bv;
    }

    const _Float16* inb = in + (size_t)n * HW * 128;
    uint4 stg[NIT];
    uint4 wreg[WNIT];

    auto issue = [&](int c0) {
        #pragma unroll
        for (int i = 0; i < NIT; ++i) {
            int t = tid + i * 256;
            uint4 v = {0u, 0u, 0u, 0u};
            if (TASKS % 256 == 0 || t < TASKS) {
                int g = t & 3, xx = (t >> 2) & (W - 1), yl = t >> LOG4W;
                int gy = y0 - 1 + yl;
                if ((unsigned)gy < (unsigned)H)
                    v = *(const uint4*)&inb[((size_t)(gy * W + xx)) * 128 + c0 + g * 8];
            }
            stg[i] = v;
        }
    };
    auto commit = [&](int c0) {
        #pragma unroll
        for (int i = 0; i < NIT; ++i) {
            int t = tid + i * 256;
            if (TASKS % 256 == 0 || t < TASKS) {
                int g = t & 3, xx = (t >> 2) & (W - 1), yl = t >> LOG4W;
                if constexpr (DO_BN) {
                    U4 u; u.v = stg[i];
                    const int cb = c0 + g * 8;
                    #pragma unroll
                    for (int j = 0; j < 8; ++j) {
                        float f = (float)u.h[j] * scsh[cb + j] + scsh[cb + j + 128];
                        u.h[j] = (_Float16)fmaxf(f, 0.f);
                    }
                    stg[i] = u.v;
                }
                *(uint4*)&xs[WOFF + (yl * XP + xx + 1) * PITCH + g * 8] = stg[i];
            }
        }
    };
    auto wissue = [&](int c0) {
        #pragma unroll
        for (int i = 0; i < WNIT; ++i) {
            int tsk = tid + i * 256;           // g fastest, then co, then tap
            int g = tsk & 3, co = (tsk >> 2) & 127, tp = tsk >> 9;
            wreg[i] = *(const uint4*)&wb[tp * 16384 + co * 128 + c0 + g * 8];
        }
    };
    auto wcommit = [&]() {
        #pragma unroll
        for (int i = 0; i < WNIT; ++i) {
            int tsk = tid + i * 256;
            int g = tsk & 3, co = (tsk >> 2) & 127, tp = tsk >> 9;
            *(uint4*)&xs[(tp * 128 + co) * WROW + g * 8] = wreg[i];
        }
    };

    int bofs[PTN];
    #pragma unroll
    for (int pt = 0; pt < PTN; ++pt) {
        int row_l = 2 * w + ((H == 32) ? (pt >> 1) : pt);
        int xb = ((H == 32) ? (pt & 1) * 16 : 0) + l15;
        bofs[pt] = WOFF + ((row_l + 1) * XP + xb + 1) * PITCH + lg * 8;
    }
    const int wlane = l15 * WROW + lg * 8;

    // prologue: chunk0 loads -> regs; commit after the zero-barrier
    issue(0);
    wissue(0);
    __syncthreads();                           // stage zeroing visible
    commit(0);
    wcommit();
    issue(32);
    wissue(32);
    __syncthreads();                           // chunk0 LDS ready

    for (int cc = 0; cc < 4; ++cc) {
        #pragma unroll
        for (int ky = -1; ky <= 1; ++ky)
            #pragma unroll
            for (int kx = -1; kx <= 1; ++kx) {
                const int t9 = (ky + 1) * 3 + (kx + 1);
                half8 bf[PTN];
                #pragma unroll
                for (int pt = 0; pt < PTN; ++pt)
                    bf[pt] = *(const half8*)&xs[bofs[pt] + (ky * XP + kx) * PITCH];
                const int wbase = t9 * (128 * WROW) + wlane;
                #pragma unroll
                for (int coh = 0; coh < 2; ++coh) {
                    half8 av[4];
                    #pragma unroll
                    for (int j = 0; j < 4; ++j)
                        av[j] = *(const half8*)&xs[wbase + (coh * 4 + j) * (16 * WROW)];
                    #pragma unroll
                    for (int j = 0; j < 4; ++j)
                        #pragma unroll
                        for (int pt = 0; pt < PTN; ++pt)
                            acc[coh * 4 + j][pt] = __builtin_amdgcn_mfma_f32_16x16x32_f16(
                                av[j], bf[pt], acc[coh * 4 + j][pt], 0, 0, 0);
                }
            }
        if (cc < 3) {
            __syncthreads();                   // all waves done reading LDS
            commit((cc + 1) * 32);             // regs (issued last chunk) -> LDS
            wcommit();
            if (cc < 2) { issue((cc + 2) * 32); wissue((cc + 2) * 32); }
            __syncthreads();                   // next chunk LDS ready
        }
    }

    // ---------------- fused epilogue: bounce -> per-pixel LRN ----------------
    __syncthreads();                           // weight LDS no longer needed
    _Float16* bx = xs + w * (NPIX * 128);
    #pragma unroll
    for (int a = 0; a < 8; ++a)
        #pragma unroll
        for (int pt = 0; pt < PTN; ++pt) {
            const int wpx = pt * 16 + l15;
            const int col = (a * 16 + lg * 4) ^ ((wpx & 7) * 8);
            U2 pk;
            pk.h[0] = (_Float16)acc[a][pt][0];
            pk.h[1] = (_Float16)acc[a][pt][1];
            pk.h[2] = (_Float16)acc[a][pt][2];
            pk.h[3] = (_Float16)acc[a][pt][3];
            *(ushort4*)&bx[wpx * 128 + col] = pk.u;
        }
    __syncthreads();

    if (H == 32 || l < 32) {
        const int px = l & (NPIX - 1);
        const int p3 = px & 7;
        U4 sv[16];
        #pragma unroll
        for (int g = 0; g < 16; ++g)
            sv[g].v = *(const uint4*)&bx[px * 128 + ((g ^ p3) * 8)];

        const int row_l = 2 * w + ((H == 32) ? (px >> 5) : (px >> 4));
        const int xo = px & (W - 1);
        const size_t gbase = ((size_t)n * HW + (size_t)(y0 + row_l) * W + xo) * 128;

        if constexpr (ADD_F) {
            #pragma unroll
            for (int g = 0; g < 16; ++g) {
                U4 fv; fv.v = *(const uint4*)&fbuf[gbase + g * 8];
                #pragma unroll
                for (int j = 0; j < 8; ++j)
                    sv[g].h[j] = (_Float16)((float)sv[g].h[j] + (float)fv.h[j]);
            }
        } else {
            #pragma unroll
            for (int g = 0; g < 16; ++g)
                *(uint4*)&fbuf[gbase + g * 8] = sv[g].v;
        }

        float ring[17], zr[9], wsum = 0.f;
        #pragma unroll
        for (int i = 0; i < 17; ++i) ring[i] = 0.f;
        #pragma unroll
        for (int i = 0; i < 9; ++i) zr[i] = 0.f;
        U4 ob;
        #pragma unroll
        for (int c = 0; c < 136; ++c) {
            float z = 0.f;
            if (c < 128) {
                float v = (float)sv[c >> 3].h[c & 7];
                z = v > 0.f ? v : 0.f;
            }
            float zz = z * z;
            wsum += zz - ring[c % 17];
            ring[c % 17] = zz;
            zr[c % 9] = z;
            if (c >= 8) {
                int o = c - 8;
                float p75 = exp2f(-0.75f * log2f(wsum * KAPPA + 1.f));
                ob.h[o & 7] = (_Float16)(zr[(c + 1) % 9] * p75);
                if ((o & 7) == 7) *(uint4*)&outp[gbase + (o & ~7)] = ob.v;
            }
        }
    }
}

// ------------------------------- maxpool(3,2,1) 32 -> 16, 8 channels/thread
__global__ __launch_bounds__(256) void pool32v(const _Float16* __restrict__ in,
                                               _Float16* __restrict__ out)
{
    const int idx = blockIdx.x * 256 + threadIdx.x;   // 524288
    const int cg = idx & 15;
    const int opix = (idx >> 4) & 255;
    const int n = idx >> 12;
    const int oy = opix >> 4, ox = opix & 15;
    const _Float16* ib = in + (size_t)n * 1024 * 128 + cg * 8;
    float m[8] = {0.f, 0.f, 0.f, 0.f, 0.f, 0.f, 0.f, 0.f};
    #pragma unroll
    for (int dy = -1; dy <= 1; ++dy) {
        int iy = 2 * oy + dy;
        if ((unsigned)iy >= 32u) continue;
        #pragma unroll
        for (int dx = -1; dx <= 1; ++dx) {
            int ix = 2 * ox + dx;
            if ((unsigned)ix >= 32u) continue;
            U4 v; v.v = *(const uint4*)&ib[(size_t)(iy * 32 + ix) * 128];
            #pragma unroll
            for (int i = 0; i < 8; ++i) m[i] = fmaxf(m[i], (float)v.h[i]);
        }
    }
    U4 o;
    #pragma unroll
    for (int i = 0; i < 8; ++i) o.h[i] = (_Float16)m[i];
    *(uint4*)&out[((size_t)n * 256 + opix) * 128 + cg * 8] = o.v;
}

// ------------- maxpool(3,2,0)+global max == max over [0,15)^2, 8 ch/thread
__global__ __launch_bounds__(256) void gmax2(const _Float16* __restrict__ in,
                                             float* __restrict__ g)
{
    const int idx = blockIdx.x * 256 + threadIdx.x;   // 2048
    const int c8 = idx & 15;
    const int n = idx >> 4;
    const _Float16* ib = in + (size_t)n * 256 * 128 + c8 * 8;
    float m[8] = {0.f, 0.f, 0.f, 0.f, 0.f, 0.f, 0.f, 0.f};
    for (int y = 0; y < 15; ++y)
        #pragma unroll
        for (int x = 0; x < 15; ++x) {
            U4 v; v.v = *(const uint4*)&ib[(size_t)(y * 16 + x) * 128];
            #pragma unroll
            for (int i = 0; i < 8; ++i) m[i] = fmaxf(m[i], (float)v.h[i]);
        }
    float* gb = g + n * 128 + c8 * 8;
    *(float4*)&gb[0] = {m[0], m[1], m[2], m[3]};
    *(float4*)&gb[4] = {m[4], m[5], m[6], m[7]};
}

// ------------------------------------------------------------------- MLP
__global__ __launch_bounds__(256) void mlp_k(
    const float* __restrict__ g, const float* __restrict__ w,
    const float* __restrict__ b, float* __restrict__ out)
{
    const int idx = blockIdx.x * 256 + threadIdx.x;
    if (idx >= 1280) return;
    const int n = idx / 10, k = idx - n * 10;
    float acc = b[k];
    for (int c = 0; c < CCH; ++c) acc += g[n * CCH + c] * w[k * CCH + c];
    out[idx] = acc;
}

// ==================================================================== launch
extern "C" void kernel_launch(void* const* d_in, const int* in_sizes, int n_in,
                              void* d_out, int out_size, void* d_ws, size_t ws_size,
                              hipStream_t stream)
{
    const float* x   = (const float*)d_in[0];
    const float* w1  = (const float*)d_in[1];
    const float* b1  = (const float*)d_in[2];
    const float* bng = (const float*)d_in[3];
    const float* bnb = (const float*)d_in[4];
    const float* fw[4] = {(const float*)d_in[5],  (const float*)d_in[8],
                          (const float*)d_in[11], (const float*)d_in[14]};
    const float* fb[4] = {(const float*)d_in[6],  (const float*)d_in[9],
                          (const float*)d_in[12], (const float*)d_in[15]};
    const float* rw[4] = {(const float*)d_in[7],  (const float*)d_in[10],
                          (const float*)d_in[13], (const float*)d_in[16]};
    const float* mw = (const float*)d_in[17];
    const float* mb = (const float*)d_in[18];
    float* out = (float*)d_out;

    _Float16* ws16 = (_Float16*)d_ws;
    _Float16* buf0 = ws16;                       // [128][1024][128] ping
    _Float16* buf1 = ws16 + 16777216;            // pong; also PH (raw pooled h)
    _Float16* Fb32 = ws16 + 2 * 16777216;        // f persistence (32x32)
    _Float16* base3 = ws16 + 3 * 16777216;
    _Float16* A16a = base3;                      // [128][256][128] ping
    _Float16* A16b = base3 + 4194304;            // pong
    _Float16* F16  = base3 + 2 * 4194304;        // f persistence (16x16)
    _Float16* Wb   = base3 + 3 * 4194304;        // 8 x [9][128][128]
    float* stats = (float*)(Wb + 8 * 147456);
    float* scsh  = stats + 256;
    float* gm    = scsh + 256;
    _Float16* Pp  = (_Float16*)(gm + 16384);     // [128][15][32][128] halo max
    _Float16* Wc1 = Pp + 7864320;                // [3][128][32]
    _Float16* PH  = buf1;

    zero_stats<<<1, 256, 0, stream>>>(stats);
    wcvt1<<<48, 256, 0, stream>>>(w1, Wc1);
    conv1m<<<2048, 256, 0, stream>>>(x, Wc1, b1, stats, PH, Pp);
    pool_fixr<<<3840, 256, 0, stream>>>(Pp, PH);
    bn_finalize<<<1, 128, 0, stream>>>(stats, bng, bnb, scsh);

    const float* lw[8] = {fw[0], rw[0], fw[1], rw[1], fw[2], rw[2], fw[3], rw[3]};
    for (int i = 0; i < 8; ++i)
        wcvt<<<576, 256, 0, stream>>>(lw[i], Wb + i * 147456);

    // 32x32 phase. First dispatch applies BN+relu inline (input = raw PH).
    // Ping-pong: buf1 -> buf0 -> buf1 -> ... ; after 8 dispatches -> buf1.
    conv3f<32, false, true><<<512, 256, 0, stream>>>(PH, Wb + 0 * 147456, fb[0], scsh, Fb32, buf0);
    _Float16* cur = buf0;
    _Float16* alt = buf1;
    for (int it = 0; it < 3; ++it) {
        conv3f<32, true, false><<<512, 256, 0, stream>>>(cur, Wb + 1 * 147456, nullptr, nullptr, Fb32, alt);
        { _Float16* t = cur; cur = alt; alt = t; }
    }
    conv3f<32, false, false><<<512, 256, 0, stream>>>(cur, Wb + 2 * 147456, fb[1], nullptr, Fb32, alt);
    { _Float16* t = cur; cur = alt; alt = t; }
    for (int it = 0; it < 3; ++it) {
        conv3f<32, true, false><<<512, 256, 0, stream>>>(cur, Wb + 3 * 147456, nullptr, nullptr, Fb32, alt);
        { _Float16* t = cur; cur = alt; alt = t; }
    }
    // cur now holds final 32x32 activations (buf1)
    pool32v<<<2048, 256, 0, stream>>>(cur, A16a);

    _Float16* cur16 = A16a;
    _Float16* alt16 = A16b;
    for (int s = 2; s < 4; ++s) {
        conv3f<16, false, false><<<256, 256, 0, stream>>>(cur16, Wb + (2*s) * 147456, fb[s], nullptr, F16, alt16);
        { _Float16* t = cur16; cur16 = alt16; alt16 = t; }
        for (int it = 0; it < 3; ++it) {
            conv3f<16, true, false><<<256, 256, 0, stream>>>(cur16, Wb + (2*s+1) * 147456, nullptr, nullptr, F16, alt16);
            { _Float16* t = cur16; cur16 = alt16; alt16 = t; }
        }
    }
    // 8 swaps -> cur16 == A16a
    gmax2<<<8, 256, 0, stream>>>(cur16, gm);
    mlp_k<<<5, 256, 0, stream>>>(gm, mw, mb, out);
}